// Round 6
// baseline (909.180 us; speedup 1.0000x reference)
//
#include <hip/hip_runtime.h>
#include <math.h>

#define S_LEN 2048
#define HID_N 4096
#define NH 32
#define NKV 8
#define HD 128
#define INIT_N 128
#define RECENT_N 512
#define HEAVY_N 512
#define SCALE_QK 0.08838834764831845f

typedef __attribute__((ext_vector_type(8))) short short8;
typedef __attribute__((ext_vector_type(4))) float float4v;

__device__ __forceinline__ unsigned short f2bf(float f) {
  unsigned u = __float_as_uint(f);
  unsigned r = (u + 0x7FFFu + ((u >> 16) & 1u)) >> 16;  // RNE (inputs finite)
  return (unsigned short)r;
}

__device__ __forceinline__ float bf2f(unsigned u) { return __uint_as_float(u << 16); }

__device__ __forceinline__ unsigned fkey16(unsigned u) {
  return (u & 0x8000u) ? ((~u) & 0xFFFFu) : (u | 0x8000u);
}

__device__ __forceinline__ void gld_lds16(const unsigned short* g, unsigned short* l) {
  __builtin_amdgcn_global_load_lds(
      (const __attribute__((address_space(1))) unsigned int*)g,
      (__attribute__((address_space(3))) unsigned int*)l, 16, 0, 0);
}

#define VMCNT(n) asm volatile("s_waitcnt vmcnt(" #n ")" ::: "memory")

// ---------------- elementwise cast fp32 -> bf16, 8 per thread ----------------
__global__ __launch_bounds__(256) void cast_bf16x8(const float* __restrict__ x,
                                                   unsigned short* __restrict__ y, int n) {
  int i = (blockIdx.x * 256 + threadIdx.x) << 3;
  if (i >= n) return;
  float4 a = *(const float4*)(x + i);
  float4 b = *(const float4*)(x + i + 4);
  union { unsigned short u[8]; short8 v; } o;
  o.u[0] = f2bf(a.x); o.u[1] = f2bf(a.y); o.u[2] = f2bf(a.z); o.u[3] = f2bf(a.w);
  o.u[4] = f2bf(b.x); o.u[5] = f2bf(b.y); o.u[6] = f2bf(b.z); o.u[7] = f2bf(b.w);
  *(short8*)(y + i) = o.v;
}

// ------------- transpose + cast: w[R][C] (row stride ldw) -> wt[C][R] bf16 ---
__global__ __launch_bounds__(256) void transpose_cast(const float* __restrict__ w,
                                                      unsigned short* __restrict__ wt,
                                                      int R, int C, int ldw) {
  __shared__ unsigned short t[64][65];
  const int c0 = blockIdx.x * 64;
  const int r0 = blockIdx.y * 64;
  const int tx = threadIdx.x & 63;
  const int ty = threadIdx.x >> 6;
#pragma unroll
  for (int i = 0; i < 16; ++i)
    t[ty + 4 * i][tx] = f2bf(w[(size_t)(r0 + ty + 4 * i) * ldw + c0 + tx]);
  __syncthreads();
#pragma unroll
  for (int i = 0; i < 16; ++i)
    wt[(size_t)(c0 + ty + 4 * i) * R + r0 + tx] = t[tx][ty + 4 * i];
}

// ------ 256x256, BK=64, 8-phase pipelined bf16 GEMM: C = A[M][K] @ BT[N][K]^T
// 8 waves (2Mx4N), per-wave C = 128x64. Linear LDS (m198 config), counted
// vmcnt (never 0 mid-loop), setprio around MFMA clusters, XCD-aware block
// swizzle (grids here are multiples of 8).
// Half-tiles: B0=n-rows[0,128), B1=[128,256), A01'={rows 0-63,128-191},
// A23'={64-127,192-255} (quadrant-paired so phase p's reads only touch
// halves certified >=1 phase earlier). Staging stream runs ~1.5 tiles ahead:
//   prologue: B0(0),B1(0),A01(0),A23(0),B0(1),B1(1),A01(1)   vmcnt(8)
//   p0(t): A23(t+1)   p1(t): B0(t+2) vmcnt(10)   p2(t): B1(t+2)
//   p3(t): A01(t+2) vmcnt(8)
__global__ __launch_bounds__(512, 2)
void gemm256(const unsigned short* __restrict__ A,
             const unsigned short* __restrict__ BT,
             float* __restrict__ C, int M, int N, int K) {
  __shared__ __align__(16) unsigned short lds[65536];  // A[2][256][64] | B[2][256][64]
  const int tid = threadIdx.x;
  const int lane = tid & 63;
  const int wid = tid >> 6;        // 0..7
  const int wr = wid >> 2;         // 0..1  (M)
  const int wc = wid & 3;          // 0..3  (N)
  const int col = lane & 15;
  const int quad = lane >> 4;

  // XCD-aware swizzle of the linear block id (nwg % 8 == 0 for our launches).
  const int gx = gridDim.x;
  const int nwg = gx * gridDim.y;
  int lin = blockIdx.y * gx + blockIdx.x;
  lin = (lin & 7) * (nwg >> 3) + (lin >> 3);
  const int m0 = (lin / gx) << 8;
  const int n0 = (lin % gx) << 8;
  const int NT = K >> 6;

  const int sdst = wid << 9;       // wave-uniform LDS chunk (tid*8 = sdst + lane*8)
  const int grow = tid >> 3;       // 0..63 row within 64-row stage inst
  const int gcol = (tid & 7) << 3; // 0..56 col (elems)

#define STG2(G, B0_, LOFF, RB0, RB1, KC)                                      \
  do {                                                                        \
    gld_lds16(G + (size_t)((B0_) + (RB0) + grow) * K + (KC) + gcol,           \
              &lds[(LOFF) + (RB0) * 64 + sdst]);                              \
    gld_lds16(G + (size_t)((B0_) + (RB1) + grow) * K + (KC) + gcol,           \
              &lds[(LOFF) + (RB1) * 64 + sdst]);                              \
  } while (0)

  float4v acc[8][4] = {};

  // ---- prologue ----
  STG2(BT, n0, 32768, 0, 64, 0);        // B0(0)
  STG2(BT, n0, 32768, 128, 192, 0);     // B1(0)
  STG2(A, m0, 0, 0, 128, 0);            // A01(0)
  STG2(A, m0, 0, 64, 192, 0);           // A23(0)
  if (NT > 1) {
    STG2(BT, n0, 32768 + 16384, 0, 64, 64);      // B0(1)
    STG2(BT, n0, 32768 + 16384, 128, 192, 64);   // B1(1)
    STG2(A, m0, 16384, 0, 128, 64);              // A01(1)
    VMCNT(8);
  } else {
    VMCNT(2);
  }
  __builtin_amdgcn_s_barrier();

#pragma unroll 1
  for (int t = 0; t < NT; ++t) {
    const int cb = (t & 1) << 14;       // current A buf elem offset (0/16384)
    const int nb = cb ^ 16384;
    const int cbB = 32768 + cb;
    const int kc1 = (t + 1) << 6;
    const int kc2 = (t + 2) << 6;
    const bool h1 = (t + 1) < NT;
    const bool h2 = (t + 2) < NT;
    const int abase = cb + (wr * 128 + col) * 64 + (quad << 3);

    // ================= phase 0 =================
    short8 b8[4][2];
#pragma unroll
    for (int ni = 0; ni < 4; ++ni)
#pragma unroll
      for (int kk = 0; kk < 2; ++kk)
        b8[ni][kk] = *(const short8*)&lds[cbB + (wc * 64 + ni * 16 + col) * 64 +
                                          (quad << 3) + kk * 32];
    {
      short8 x0 = *(const short8*)&lds[abase + 0 * 64];
      short8 x1 = *(const short8*)&lds[abase + 0 * 64 + 32];
      short8 x2 = *(const short8*)&lds[abase + 16 * 64];
      short8 x3 = *(const short8*)&lds[abase + 16 * 64 + 32];
      if (h1) STG2(A, m0, nb, 64, 192, kc1);   // A23(t+1)
      __builtin_amdgcn_s_barrier();
      asm volatile("s_waitcnt lgkmcnt(0)" ::: "memory");
      __builtin_amdgcn_sched_barrier(0);
      __builtin_amdgcn_s_setprio(1);
#pragma unroll
      for (int ni = 0; ni < 4; ++ni) {
        acc[0][ni] = __builtin_amdgcn_mfma_f32_16x16x32_bf16(x0, b8[ni][0], acc[0][ni], 0, 0, 0);
        acc[0][ni] = __builtin_amdgcn_mfma_f32_16x16x32_bf16(x1, b8[ni][1], acc[0][ni], 0, 0, 0);
        acc[1][ni] = __builtin_amdgcn_mfma_f32_16x16x32_bf16(x2, b8[ni][0], acc[1][ni], 0, 0, 0);
        acc[1][ni] = __builtin_amdgcn_mfma_f32_16x16x32_bf16(x3, b8[ni][1], acc[1][ni], 0, 0, 0);
      }
      __builtin_amdgcn_s_setprio(0);
      __builtin_amdgcn_s_barrier();
    }
    // ================= phase 1 =================
    {
      short8 x0 = *(const short8*)&lds[abase + 32 * 64];
      short8 x1 = *(const short8*)&lds[abase + 32 * 64 + 32];
      short8 x2 = *(const short8*)&lds[abase + 48 * 64];
      short8 x3 = *(const short8*)&lds[abase + 48 * 64 + 32];
      if (h2) STG2(BT, n0, cbB, 0, 64, kc2);   // B0(t+2)
      if (h2) { VMCNT(10); } else if (h1) { VMCNT(8); } else { VMCNT(0); }  // certify A23(t)
      __builtin_amdgcn_s_barrier();
      asm volatile("s_waitcnt lgkmcnt(0)" ::: "memory");
      __builtin_amdgcn_sched_barrier(0);
      __builtin_amdgcn_s_setprio(1);
#pragma unroll
      for (int ni = 0; ni < 4; ++ni) {
        acc[2][ni] = __builtin_amdgcn_mfma_f32_16x16x32_bf16(x0, b8[ni][0], acc[2][ni], 0, 0, 0);
        acc[2][ni] = __builtin_amdgcn_mfma_f32_16x16x32_bf16(x1, b8[ni][1], acc[2][ni], 0, 0, 0);
        acc[3][ni] = __builtin_amdgcn_mfma_f32_16x16x32_bf16(x2, b8[ni][0], acc[3][ni], 0, 0, 0);
        acc[3][ni] = __builtin_amdgcn_mfma_f32_16x16x32_bf16(x3, b8[ni][1], acc[3][ni], 0, 0, 0);
      }
      __builtin_amdgcn_s_setprio(0);
      __builtin_amdgcn_s_barrier();
    }
    // ================= phase 2 =================
    {
      short8 x0 = *(const short8*)&lds[abase + 64 * 64];
      short8 x1 = *(const short8*)&lds[abase + 64 * 64 + 32];
      short8 x2 = *(const short8*)&lds[abase + 80 * 64];
      short8 x3 = *(const short8*)&lds[abase + 80 * 64 + 32];
      if (h2) STG2(BT, n0, cbB, 128, 192, kc2);  // B1(t+2)
      __builtin_amdgcn_s_barrier();
      asm volatile("s_waitcnt lgkmcnt(0)" ::: "memory");
      __builtin_amdgcn_sched_barrier(0);
      __builtin_amdgcn_s_setprio(1);
#pragma unroll
      for (int ni = 0; ni < 4; ++ni) {
        acc[4][ni] = __builtin_amdgcn_mfma_f32_16x16x32_bf16(x0, b8[ni][0], acc[4][ni], 0, 0, 0);
        acc[4][ni] = __builtin_amdgcn_mfma_f32_16x16x32_bf16(x1, b8[ni][1], acc[4][ni], 0, 0, 0);
        acc[5][ni] = __builtin_amdgcn_mfma_f32_16x16x32_bf16(x2, b8[ni][0], acc[5][ni], 0, 0, 0);
        acc[5][ni] = __builtin_amdgcn_mfma_f32_16x16x32_bf16(x3, b8[ni][1], acc[5][ni], 0, 0, 0);
      }
      __builtin_amdgcn_s_setprio(0);
      __builtin_amdgcn_s_barrier();
    }
    // ================= phase 3 =================
    {
      short8 x0 = *(const short8*)&lds[abase + 96 * 64];
      short8 x1 = *(const short8*)&lds[abase + 96 * 64 + 32];
      short8 x2 = *(const short8*)&lds[abase + 112 * 64];
      short8 x3 = *(const short8*)&lds[abase + 112 * 64 + 32];
      if (h2) STG2(A, m0, cb, 0, 128, kc2);      // A01(t+2)
      if (h2) { VMCNT(8); } else if (h1) { VMCNT(2); }  // certify B(t+1)+A01(t+1)
      __builtin_amdgcn_s_barrier();
      asm volatile("s_waitcnt lgkmcnt(0)" ::: "memory");
      __builtin_amdgcn_sched_barrier(0);
      __builtin_amdgcn_s_setprio(1);
#pragma unroll
      for (int ni = 0; ni < 4; ++ni) {
        acc[6][ni] = __builtin_amdgcn_mfma_f32_16x16x32_bf16(x0, b8[ni][0], acc[6][ni], 0, 0, 0);
        acc[6][ni] = __builtin_amdgcn_mfma_f32_16x16x32_bf16(x1, b8[ni][1], acc[6][ni], 0, 0, 0);
        acc[7][ni] = __builtin_amdgcn_mfma_f32_16x16x32_bf16(x2, b8[ni][0], acc[7][ni], 0, 0, 0);
        acc[7][ni] = __builtin_amdgcn_mfma_f32_16x16x32_bf16(x3, b8[ni][1], acc[7][ni], 0, 0, 0);
      }
      __builtin_amdgcn_s_setprio(0);
      __builtin_amdgcn_s_barrier();
    }
  }

#pragma unroll
  for (int mi = 0; mi < 8; ++mi)
#pragma unroll
    for (int ni = 0; ni < 4; ++ni) {
      size_t base = (size_t)(m0 + wr * 128 + mi * 16 + (quad << 2)) * N +
                    n0 + wc * 64 + ni * 16 + col;
      C[base] = acc[mi][ni][0];
      C[base + N] = acc[mi][ni][1];
      C[base + 2 * (size_t)N] = acc[mi][ni][2];
      C[base + 3 * (size_t)N] = acc[mi][ni][3];
    }
#undef STG2
}

// ------- RoPE + cast to bf16: x[S][*] (stride ldx) -> y (stride ldy) bf16 ----
__global__ __launch_bounds__(256) void rope_cast(const float* __restrict__ x,
                                                 unsigned short* __restrict__ y,
                                                 int nheads, int ldx, int ldy) {
  int idx = blockIdx.x * 256 + threadIdx.x;
  int i = idx & 63;
  int rest = idx >> 6;
  int hh = rest % nheads;
  int s = rest / nheads;
  if (s >= S_LEN) return;
  const float* p = x + (size_t)s * ldx + hh * HD;
  unsigned short* o = y + (size_t)s * ldy + hh * HD;
  float inv = (float)(1.0 / pow(10000.0, (double)(2 * i) / 128.0));
  float ang = (float)s * inv;
  float c = cosf(ang);
  float sn = sinf(ang);
  float x1 = p[i];
  float x2 = p[i + 64];
  o[i] = f2bf(x1 * c - x2 * sn);
  o[i + 64] = f2bf(x2 * c + x1 * sn);
}

// ------------ fused heavy-hitter attention, MFMA, 16 q-rows, 8 waves ---------
// (round-3 configuration: the round-4 16-wave variant regressed — occupancy
// doubled but VALUBusy/duration unchanged, so attn is not wave-starved.)
template <int SMAX>
__global__ __launch_bounds__(512, 4)
void attn_mfma(const unsigned short* __restrict__ qb,
               const unsigned short* __restrict__ kb,
               const unsigned short* __restrict__ vt,
               unsigned short* __restrict__ ao16, int qbase) {
  const int qi0 = (qbase + blockIdx.x) << 4;
  const int h = blockIdx.y;
  const int g = h >> 2;
  const int tid = threadIdx.x;
  const int lane = tid & 63;
  const int wid = tid >> 6;          // 0..7
  const int col = lane & 15;
  const int quad = lane >> 4;
  const int nkm = qi0 + 16;
  const int nkm32 = (nkm + 31) & ~31;

  __shared__ __align__(16) unsigned short sc[16 * SMAX];
  __shared__ float sumv[16];

  // ---- Phase A: S = (Q K^T) * scale via MFMA, tiles stride-8, 2 deep ----
  short8 qf[4];
  {
    const unsigned short* qrow = qb + (size_t)(qi0 + col) * (NH * HD) + h * HD + (quad << 3);
#pragma unroll
    for (int dt = 0; dt < 4; ++dt) qf[dt] = *(const short8*)(qrow + dt * 32);
  }
  const int ntiles = nkm >> 4;
  int t = wid;
  for (; t + 8 < ntiles; t += 16) {
    const int k0a = t << 4;
    const int k0b = (t + 8) << 4;
    const unsigned short* kra = kb + (size_t)(k0a + col) * (NKV * HD) + g * HD + (quad << 3);
    const unsigned short* krb = kb + (size_t)(k0b + col) * (NKV * HD) + g * HD + (quad << 3);
    short8 kfa[4], kfb[4];
#pragma unroll
    for (int dt = 0; dt < 4; ++dt) kfa[dt] = *(const short8*)(kra + dt * 32);
#pragma unroll
    for (int dt = 0; dt < 4; ++dt) kfb[dt] = *(const short8*)(krb + dt * 32);
    float4v acca = {}, accb = {};
#pragma unroll
    for (int dt = 0; dt < 4; ++dt) {
      acca = __builtin_amdgcn_mfma_f32_16x16x32_bf16(qf[dt], kfa[dt], acca, 0, 0, 0);
      accb = __builtin_amdgcn_mfma_f32_16x16x32_bf16(qf[dt], kfb[dt], accb, 0, 0, 0);
    }
#pragma unroll
    for (int r = 0; r < 4; ++r) {
      int q = (quad << 2) + r;
      sc[(q * SMAX + k0a + col) ^ ((q & 7) << 3)] = f2bf(acca[r] * SCALE_QK);
      sc[(q * SMAX + k0b + col) ^ ((q & 7) << 3)] = f2bf(accb[r] * SCALE_QK);
    }
  }
  if (t < ntiles) {
    const int k0 = t << 4;
    const unsigned short* krow = kb + (size_t)(k0 + col) * (NKV * HD) + g * HD + (quad << 3);
    float4v acc = {};
#pragma unroll
    for (int dt = 0; dt < 4; ++dt) {
      short8 kf = *(const short8*)(krow + dt * 32);
      acc = __builtin_amdgcn_mfma_f32_16x16x32_bf16(qf[dt], kf, acc, 0, 0, 0);
    }
#pragma unroll
    for (int r = 0; r < 4; ++r) {
      int q = (quad << 2) + r;
      sc[(q * SMAX + k0 + col) ^ ((q & 7) << 3)] = f2bf(acc[r] * SCALE_QK);
    }
  }
  __syncthreads();

  // ---- Phase B: per-row top-k threshold + softmax (wave w owns rows 2w,2w+1) ----
  const unsigned long long lmlt = (1ull << lane) - 1ull;
#pragma unroll 1
  for (int rr = 0; rr < 2; ++rr) {
    const int r = (wid << 1) + rr;
    const int qi = qi0 + r;
    const int mhi = qi - RECENT_N;       // last middle index
    const int m = mhi - INIT_N + 1;      // middle count
    const bool need = (SMAX > 1024) && (m > HEAVY_N);
    const unsigned swz = (r & 7) << 3;
    const int rbase = r * SMAX;

    unsigned T = 0, rem = 0;
    if (need) {
      // 16-bit radix select over bf16 score keys; pads (0) never match target.
      unsigned myk[22];
#pragma unroll
      for (int j = 0; j < 11; ++j) {
        int off = (lane + (j << 6)) << 1;  // 0..1406 step 2, covers m <= 1408
        unsigned u = *(const unsigned*)&sc[(rbase + INIT_N + off) ^ swz];
        unsigned f0 = fkey16(u & 0xFFFFu);
        unsigned f1 = fkey16(u >> 16);
        myk[2 * j] = (off < m) ? f0 : 0u;
        myk[2 * j + 1] = (off + 1 < m) ? f1 : 0u;
      }
      unsigned prefix = 0, rm = HEAVY_N;
#pragma unroll 1
      for (int bit = 15; bit >= 0; --bit) {
        unsigned target = (prefix >> bit) | 1u;
        unsigned cnt = 0;
#pragma unroll
        for (int j = 0; j < 22; ++j)
          cnt += (unsigned)__popcll(__ballot((myk[j] >> bit) == target));
        if (cnt >= rm) prefix |= (1u << bit);
        else rm -= cnt;
      }
      T = prefix;
      rem = rm;
    }

    // Max over causal range only: the causal max is always in the selected set.
    float mx = -3.402823466e38f;
#pragma unroll 1
    for (int c0 = 0; c0 <= qi; c0 += 128) {
      int k2 = c0 + (lane << 1);
      unsigned u = *(const unsigned*)&sc[(rbase + k2) ^ swz];
      float s0 = bf2f(u & 0xFFFFu);
      float s1 = bf2f(u >> 16);
      if (k2 <= qi) mx = fmaxf(mx, s0);
      if (k2 + 1 <= qi) mx = fmaxf(mx, s1);
    }
#pragma unroll
    for (int off = 32; off; off >>= 1) mx = fmaxf(mx, __shfl_xor(mx, off, 64));

    float sum = 0.f;
    unsigned cum = 0;
#pragma unroll 1
    for (int c0 = 0; c0 < nkm32; c0 += 128) {
      int k2 = c0 + (lane << 1);
      int idx = (rbase + k2) ^ swz;
      unsigned u = *(const unsigned*)&sc[idx];
      bool ic0 = k2 <= qi, ic1 = (k2 + 1) <= qi;
      bool sel0, sel1;
      if (!need) {
        sel0 = ic0;
        sel1 = ic1;
      } else {
        bool mid0 = ic0 && (k2 >= INIT_N) && (k2 <= mhi);
        bool mid1 = ic1 && (k2 + 1 >= INIT_N) && (k2 + 1 <= mhi);
        unsigned f0 = fkey16(u & 0xFFFFu);
        unsigned f1 = fkey16(u >> 16);
        unsigned long long eq0 = __ballot(mid0 && (f0 == T));
        unsigned long long eq1 = __ballot(mid1 && (f1 == T));
        unsigned pre0 = cum + (unsigned)__popcll(eq0 & lmlt) + (unsigned)__popcll(eq1 & lmlt);
        unsigned pre1 = pre0 + (unsigned)((eq0 >> lane) & 1ull);
        sel0 = ic0 && (!mid0 || (f0 > T) || ((f0 == T) && (pre0 < rem)));
        sel1 = ic1 && (!mid1 || (f1 > T) || ((f1 == T) && (pre1 < rem)));
        cum += (unsigned)__popcll(eq0) + (unsigned)__popcll(eq1);
      }
      float e0 = sel0 ? __expf(bf2f(u & 0xFFFFu) - mx) : 0.f;
      float e1 = sel1 ? __expf(bf2f(u >> 16) - mx) : 0.f;
      sum += e0 + e1;
      *(unsigned*)&sc[idx] = (unsigned)f2bf(e0) | ((unsigned)f2bf(e1) << 16);
    }
#pragma unroll
    for (int off = 32; off; off >>= 1) sum += __shfl_xor(sum, off, 64);
    if (lane == 0) sumv[r] = sum;
  }
  __syncthreads();

  // ---- Phase C: O = P V via MFMA; wave w owns d-slice [16w, 16w+16) --------
  float4v a0 = {}, b0 = {};
  const int db = wid << 4;
  const unsigned short* vrow = vt + (size_t)(g * HD + db + col) * S_LEN + (quad << 3);
  const unsigned pswz = (unsigned)((col & 7) << 3);
  int k0 = 0;
  for (; k0 + 32 < nkm32; k0 += 64) {
    short8 pf0 = *(const short8*)&sc[(col * SMAX + k0 + (quad << 3)) ^ pswz];
    short8 pf1 = *(const short8*)&sc[(col * SMAX + k0 + 32 + (quad << 3)) ^ pswz];
    short8 v0 = *(const short8*)(vrow + k0);
    short8 v1 = *(const short8*)(vrow + k0 + 32);
    a0 = __builtin_amdgcn_mfma_f32_16x16x32_bf16(pf0, v0, a0, 0, 0, 0);
    b0 = __builtin_amdgcn_mfma_f32_16x16x32_bf16(pf1, v1, b0, 0, 0, 0);
  }
  if (k0 < nkm32) {
    short8 pf = *(const short8*)&sc[(col * SMAX + k0 + (quad << 3)) ^ pswz];
    short8 v0 = *(const short8*)(vrow + k0);
    a0 = __builtin_amdgcn_mfma_f32_16x16x32_bf16(pf, v0, a0, 0, 0, 0);
  }
  a0 += b0;
#pragma unroll
  for (int r = 0; r < 4; ++r) {
    int qq = (quad << 2) + r;
    float inv = 1.0f / sumv[qq];
    size_t o = (size_t)(qi0 + qq) * (NH * HD) + h * HD + db;
    ao16[o + col] = f2bf(a0[r] * inv);
  }
}

// ---------------------------------------------------------------------------
extern "C" void kernel_launch(void* const* d_in, const int* in_sizes, int n_in,
                              void* d_out, int out_size, void* d_ws, size_t ws_size,
                              hipStream_t stream) {
  const float* hidden = (const float*)d_in[0];
  const float* wq = (const float*)d_in[1];
  const float* wk = (const float*)d_in[2];
  const float* wv = (const float*)d_in[3];
  const float* wo = (const float*)d_in[4];
  float* out = (float*)d_out;

  // workspace layout (floats), 30M floats = 120 MB used:
  //  [ 0M,12M)  qkv f32 [S][6144] (q | k | v)
  //  [12M,16M)  qb16 bf16 [S][NH*HD]
  //  [16M,20M)  hb bf16 [S][HID]           -> reused as aob bf16
  //  [20M,32M)  wqkvT bf16 [6144][4096]    -> after QKV gemm reused:
  //               [20M,28M) woT bf16 [4096][4096]
  //               [28M,29M) kb16 bf16 [S][NKV*HD]
  //               [29M,30M) vT16 bf16 [NKV*HD][S]
  float* ws = (float*)d_ws;
  const size_t M1 = 1024 * 1024;
  float* qkv = ws;
  unsigned short* qb16 = (unsigned short*)(ws + 12 * M1);
  unsigned short* hb = (unsigned short*)(ws + 16 * M1);
  unsigned short* aob = hb;
  unsigned short* wqkvT = (unsigned short*)(ws + 20 * M1);
  unsigned short* woT = wqkvT;
  unsigned short* kb16 = (unsigned short*)(ws + 28 * M1);
  unsigned short* vT16 = (unsigned short*)(ws + 29 * M1);

  dim3 blk(256);
  const int NE = S_LEN * HID_N;  // 8,388,608

  cast_bf16x8<<<NE / 2048, blk, 0, stream>>>(hidden, hb, NE);
  transpose_cast<<<dim3(HID_N / 64, HID_N / 64), blk, 0, stream>>>(wq, wqkvT, HID_N, HID_N, HID_N);
  transpose_cast<<<dim3((NKV * HD) / 64, HID_N / 64), blk, 0, stream>>>(
      wk, wqkvT + (size_t)HID_N * HID_N, HID_N, NKV * HD, NKV * HD);
  transpose_cast<<<dim3((NKV * HD) / 64, HID_N / 64), blk, 0, stream>>>(
      wv, wqkvT + (size_t)(HID_N + NKV * HD) * HID_N, HID_N, NKV * HD, NKV * HD);

  // fused QKV projection: [2048][4096] @ [4096][6144] -> [2048][6144]
  gemm256<<<dim3(6144 / 256, S_LEN / 256), dim3(512), 0, stream>>>(hb, wqkvT, qkv, S_LEN, 6144, HID_N);

  transpose_cast<<<dim3(HID_N / 64, HID_N / 64), blk, 0, stream>>>(wo, woT, NH * HD, HID_N, HID_N);

  rope_cast<<<(S_LEN * NH * 64) / 256, blk, 0, stream>>>(qkv, qb16, NH, 6144, NH * HD);
  rope_cast<<<(S_LEN * NKV * 64) / 256, blk, 0, stream>>>(qkv + HID_N, kb16, NKV, 6144, NKV * HD);
  transpose_cast<<<dim3((NKV * HD) / 64, S_LEN / 64), blk, 0, stream>>>(
      qkv + HID_N + NKV * HD, vT16, S_LEN, NKV * HD, 6144);

  attn_mfma<2048><<<dim3(64, NH), dim3(512), 0, stream>>>(qb16, kb16, vT16, aob, 64);
  attn_mfma<1024><<<dim3(64, NH), dim3(512), 0, stream>>>(qb16, kb16, vT16, aob, 0);

  gemm256<<<dim3(HID_N / 256, S_LEN / 256), dim3(512), 0, stream>>>(aob, woT, out, S_LEN, HID_N, NH * HD);
}

// Round 7
// 812.156 us; speedup vs baseline: 1.1195x; 1.1195x over previous
//
#include <hip/hip_runtime.h>
#include <math.h>

#define S_LEN 2048
#define HID_N 4096
#define NH 32
#define NKV 8
#define HD 128
#define INIT_N 128
#define RECENT_N 512
#define HEAVY_N 512
#define SCALE_QK 0.08838834764831845f

typedef __attribute__((ext_vector_type(8))) short short8;
typedef __attribute__((ext_vector_type(4))) float float4v;

__device__ __forceinline__ unsigned short f2bf(float f) {
  unsigned u = __float_as_uint(f);
  unsigned r = (u + 0x7FFFu + ((u >> 16) & 1u)) >> 16;  // RNE (inputs finite)
  return (unsigned short)r;
}

__device__ __forceinline__ float bf2f(unsigned u) { return __uint_as_float(u << 16); }

__device__ __forceinline__ unsigned fkey16(unsigned u) {
  return (u & 0x8000u) ? ((~u) & 0xFFFFu) : (u | 0x8000u);
}

__device__ __forceinline__ void gld_lds16(const unsigned short* g, unsigned short* l) {
  __builtin_amdgcn_global_load_lds(
      (const __attribute__((address_space(1))) unsigned int*)g,
      (__attribute__((address_space(3))) unsigned int*)l, 16, 0, 0);
}

#define VMCNT(n) asm volatile("s_waitcnt vmcnt(" #n ")" ::: "memory")

// ---------------- elementwise cast fp32 -> bf16, 8 per thread ----------------
__global__ __launch_bounds__(256) void cast_bf16x8(const float* __restrict__ x,
                                                   unsigned short* __restrict__ y, int n) {
  int i = (blockIdx.x * 256 + threadIdx.x) << 3;
  if (i >= n) return;
  float4 a = *(const float4*)(x + i);
  float4 b = *(const float4*)(x + i + 4);
  union { unsigned short u[8]; short8 v; } o;
  o.u[0] = f2bf(a.x); o.u[1] = f2bf(a.y); o.u[2] = f2bf(a.z); o.u[3] = f2bf(a.w);
  o.u[4] = f2bf(b.x); o.u[5] = f2bf(b.y); o.u[6] = f2bf(b.z); o.u[7] = f2bf(b.w);
  *(short8*)(y + i) = o.v;
}

// ---------------- y += x, float4 per thread ---------------------------------
__global__ __launch_bounds__(256) void add_f32x4(float* __restrict__ y,
                                                 const float* __restrict__ x, int n) {
  int i = (blockIdx.x * 256 + threadIdx.x) << 2;
  if (i >= n) return;
  float4 a = *(const float4*)(y + i);
  float4 b = *(const float4*)(x + i);
  a.x += b.x; a.y += b.y; a.z += b.z; a.w += b.w;
  *(float4*)(y + i) = a;
}

// ------------- transpose + cast: w[R][C] (row stride ldw) -> wt[C][R] bf16 ---
__global__ __launch_bounds__(256) void transpose_cast(const float* __restrict__ w,
                                                      unsigned short* __restrict__ wt,
                                                      int R, int C, int ldw) {
  __shared__ unsigned short t[64][65];
  const int c0 = blockIdx.x * 64;
  const int r0 = blockIdx.y * 64;
  const int tx = threadIdx.x & 63;
  const int ty = threadIdx.x >> 6;
#pragma unroll
  for (int i = 0; i < 16; ++i)
    t[ty + 4 * i][tx] = f2bf(w[(size_t)(r0 + ty + 4 * i) * ldw + c0 + tx]);
  __syncthreads();
#pragma unroll
  for (int i = 0; i < 16; ++i)
    wt[(size_t)(c0 + ty + 4 * i) * R + r0 + tx] = t[tx][ty + 4 * i];
}

// ------ 256x256, BK=64, 8-phase pipelined bf16 GEMM: C = A[M][K] @ BT[N][K]^T
// 8 waves (2Mx4N), per-wave C = 128x64. T2 XOR-swizzled LDS (linear dest +
// pre-swizzled global source + swizzled ds_read, rule 21), counted vmcnt
// (never 0 mid-loop), setprio around MFMA clusters, XCD-aware block swizzle.
// blockIdx.z selects a K-slice of KT (split-K; partials to C0/C1).
// Staging stream ~1.5 tiles ahead:
//   prologue: B0(0),B1(0),A01(0),A23(0),B0(1),B1(1),A01(1)   vmcnt(8)
//   p0(t): A23(t+1)   p1(t): B0(t+2) vmcnt(10)   p2(t): B1(t+2)
//   p3(t): A01(t+2) vmcnt(8)
__global__ __launch_bounds__(512, 2)
void gemm256(const unsigned short* __restrict__ A,
             const unsigned short* __restrict__ BT,
             float* __restrict__ C0, float* __restrict__ C1,
             int M, int N, int KT, int lda, int ldb) {
  __shared__ __align__(16) unsigned short lds[65536];  // A[2][256][64] | B[2][256][64]
  const int tid = threadIdx.x;
  const int lane = tid & 63;
  const int wid = tid >> 6;        // 0..7
  const int wr = wid >> 2;         // 0..1  (M)
  const int wc = wid & 3;          // 0..3  (N)
  const int col = lane & 15;
  const int quad = lane >> 4;

  A += (size_t)blockIdx.z * KT;
  BT += (size_t)blockIdx.z * KT;
  float* __restrict__ C = blockIdx.z ? C1 : C0;

  // XCD-aware swizzle of the per-slice linear block id (nwg % 8 == 0 here).
  const int gx = gridDim.x;
  const int nwg = gx * gridDim.y;
  int lin = blockIdx.y * gx + blockIdx.x;
  lin = (lin & 7) * (nwg >> 3) + (lin >> 3);
  const int m0 = (lin / gx) << 8;
  const int n0 = (lin % gx) << 8;
  const int NT = KT >> 6;

  const int sdst = wid << 9;       // wave-uniform LDS chunk (tid*8 = sdst + lane*8)
  const int grow = tid >> 3;       // 0..63 row within 64-row stage inst
  // T2: pre-swizzled global source column (dest row&7 == grow&7)
  const int gcolsw = ((tid & 7) << 3) ^ (((tid >> 3) & 7) << 3);
  // T2: read-side XOR (fragment rows have row&7 == col&7)
  const int o0 = ((quad << 3) ^ ((col & 7) << 3));   // k-group 0
  const int o1 = o0 ^ 32;                            // k-group +32

#define STG2(G, LD, GB, LOFF, RB0, RB1, KC)                                   \
  do {                                                                        \
    gld_lds16(G + (size_t)((GB) + (RB0) + grow) * (LD) + (KC) + gcolsw,       \
              &lds[(LOFF) + (RB0) * 64 + sdst]);                              \
    gld_lds16(G + (size_t)((GB) + (RB1) + grow) * (LD) + (KC) + gcolsw,       \
              &lds[(LOFF) + (RB1) * 64 + sdst]);                              \
  } while (0)

  float4v acc[8][4] = {};

  // ---- prologue ----
  STG2(BT, ldb, n0, 32768, 0, 64, 0);        // B0(0)
  STG2(BT, ldb, n0, 32768, 128, 192, 0);     // B1(0)
  STG2(A, lda, m0, 0, 0, 128, 0);            // A01(0)
  STG2(A, lda, m0, 0, 64, 192, 0);           // A23(0)
  if (NT > 1) {
    STG2(BT, ldb, n0, 32768 + 16384, 0, 64, 64);      // B0(1)
    STG2(BT, ldb, n0, 32768 + 16384, 128, 192, 64);   // B1(1)
    STG2(A, lda, m0, 16384, 0, 128, 64);              // A01(1)
    VMCNT(8);
  } else {
    VMCNT(2);
  }
  __builtin_amdgcn_s_barrier();

#pragma unroll 1
  for (int t = 0; t < NT; ++t) {
    const int cb = (t & 1) << 14;       // current A buf elem offset (0/16384)
    const int nb = cb ^ 16384;
    const int cbB = 32768 + cb;
    const int kc1 = (t + 1) << 6;
    const int kc2 = (t + 2) << 6;
    const bool h1 = (t + 1) < NT;
    const bool h2 = (t + 2) < NT;
    const int abase = cb + (wr * 128 + col) * 64;

    // ================= phase 0 =================
    short8 b8[4][2];
#pragma unroll
    for (int ni = 0; ni < 4; ++ni) {
      const int bb = cbB + (wc * 64 + ni * 16 + col) * 64;
      b8[ni][0] = *(const short8*)&lds[bb + o0];
      b8[ni][1] = *(const short8*)&lds[bb + o1];
    }
    {
      short8 x0 = *(const short8*)&lds[abase + 0 * 64 + o0];
      short8 x1 = *(const short8*)&lds[abase + 0 * 64 + o1];
      short8 x2 = *(const short8*)&lds[abase + 16 * 64 + o0];
      short8 x3 = *(const short8*)&lds[abase + 16 * 64 + o1];
      if (h1) STG2(A, lda, m0, nb, 64, 192, kc1);   // A23(t+1)
      __builtin_amdgcn_s_barrier();
      asm volatile("s_waitcnt lgkmcnt(0)" ::: "memory");
      __builtin_amdgcn_sched_barrier(0);
      __builtin_amdgcn_s_setprio(1);
#pragma unroll
      for (int ni = 0; ni < 4; ++ni) {
        acc[0][ni] = __builtin_amdgcn_mfma_f32_16x16x32_bf16(x0, b8[ni][0], acc[0][ni], 0, 0, 0);
        acc[0][ni] = __builtin_amdgcn_mfma_f32_16x16x32_bf16(x1, b8[ni][1], acc[0][ni], 0, 0, 0);
        acc[1][ni] = __builtin_amdgcn_mfma_f32_16x16x32_bf16(x2, b8[ni][0], acc[1][ni], 0, 0, 0);
        acc[1][ni] = __builtin_amdgcn_mfma_f32_16x16x32_bf16(x3, b8[ni][1], acc[1][ni], 0, 0, 0);
      }
      __builtin_amdgcn_s_setprio(0);
      __builtin_amdgcn_s_barrier();
    }
    // ================= phase 1 =================
    {
      short8 x0 = *(const short8*)&lds[abase + 32 * 64 + o0];
      short8 x1 = *(const short8*)&lds[abase + 32 * 64 + o1];
      short8 x2 = *(const short8*)&lds[abase + 48 * 64 + o0];
      short8 x3 = *(const short8*)&lds[abase + 48 * 64 + o1];
      if (h2) STG2(BT, ldb, n0, cbB, 0, 64, kc2);   // B0(t+2)
      if (h2) { VMCNT(10); } else if (h1) { VMCNT(8); } else { VMCNT(0); }  // certify A23(t)
      __builtin_amdgcn_s_barrier();
      asm volatile("s_waitcnt lgkmcnt(0)" ::: "memory");
      __builtin_amdgcn_sched_barrier(0);
      __builtin_amdgcn_s_setprio(1);
#pragma unroll
      for (int ni = 0; ni < 4; ++ni) {
        acc[2][ni] = __builtin_amdgcn_mfma_f32_16x16x32_bf16(x0, b8[ni][0], acc[2][ni], 0, 0, 0);
        acc[2][ni] = __builtin_amdgcn_mfma_f32_16x16x32_bf16(x1, b8[ni][1], acc[2][ni], 0, 0, 0);
        acc[3][ni] = __builtin_amdgcn_mfma_f32_16x16x32_bf16(x2, b8[ni][0], acc[3][ni], 0, 0, 0);
        acc[3][ni] = __builtin_amdgcn_mfma_f32_16x16x32_bf16(x3, b8[ni][1], acc[3][ni], 0, 0, 0);
      }
      __builtin_amdgcn_s_setprio(0);
      __builtin_amdgcn_s_barrier();
    }
    // ================= phase 2 =================
    {
      short8 x0 = *(const short8*)&lds[abase + 64 * 64 + o0];
      short8 x1 = *(const short8*)&lds[abase + 64 * 64 + o1];
      short8 x2 = *(const short8*)&lds[abase + 80 * 64 + o0];
      short8 x3 = *(const short8*)&lds[abase + 80 * 64 + o1];
      if (h2) STG2(BT, ldb, n0, cbB, 128, 192, kc2);  // B1(t+2)
      __builtin_amdgcn_s_barrier();
      asm volatile("s_waitcnt lgkmcnt(0)" ::: "memory");
      __builtin_amdgcn_sched_barrier(0);
      __builtin_amdgcn_s_setprio(1);
#pragma unroll
      for (int ni = 0; ni < 4; ++ni) {
        acc[4][ni] = __builtin_amdgcn_mfma_f32_16x16x32_bf16(x0, b8[ni][0], acc[4][ni], 0, 0, 0);
        acc[4][ni] = __builtin_amdgcn_mfma_f32_16x16x32_bf16(x1, b8[ni][1], acc[4][ni], 0, 0, 0);
        acc[5][ni] = __builtin_amdgcn_mfma_f32_16x16x32_bf16(x2, b8[ni][0], acc[5][ni], 0, 0, 0);
        acc[5][ni] = __builtin_amdgcn_mfma_f32_16x16x32_bf16(x3, b8[ni][1], acc[5][ni], 0, 0, 0);
      }
      __builtin_amdgcn_s_setprio(0);
      __builtin_amdgcn_s_barrier();
    }
    // ================= phase 3 =================
    {
      short8 x0 = *(const short8*)&lds[abase + 96 * 64 + o0];
      short8 x1 = *(const short8*)&lds[abase + 96 * 64 + o1];
      short8 x2 = *(const short8*)&lds[abase + 112 * 64 + o0];
      short8 x3 = *(const short8*)&lds[abase + 112 * 64 + o1];
      if (h2) STG2(A, lda, m0, cb, 0, 128, kc2);      // A01(t+2)
      if (h2) { VMCNT(8); } else if (h1) { VMCNT(2); }  // certify B(t+1)+A01(t+1)
      __builtin_amdgcn_s_barrier();
      asm volatile("s_waitcnt lgkmcnt(0)" ::: "memory");
      __builtin_amdgcn_sched_barrier(0);
      __builtin_amdgcn_s_setprio(1);
#pragma unroll
      for (int ni = 0; ni < 4; ++ni) {
        acc[6][ni] = __builtin_amdgcn_mfma_f32_16x16x32_bf16(x0, b8[ni][0], acc[6][ni], 0, 0, 0);
        acc[6][ni] = __builtin_amdgcn_mfma_f32_16x16x32_bf16(x1, b8[ni][1], acc[6][ni], 0, 0, 0);
        acc[7][ni] = __builtin_amdgcn_mfma_f32_16x16x32_bf16(x2, b8[ni][0], acc[7][ni], 0, 0, 0);
        acc[7][ni] = __builtin_amdgcn_mfma_f32_16x16x32_bf16(x3, b8[ni][1], acc[7][ni], 0, 0, 0);
      }
      __builtin_amdgcn_s_setprio(0);
      __builtin_amdgcn_s_barrier();
    }
  }

#pragma unroll
  for (int mi = 0; mi < 8; ++mi)
#pragma unroll
    for (int ni = 0; ni < 4; ++ni) {
      size_t base = (size_t)(m0 + wr * 128 + mi * 16 + (quad << 2)) * N +
                    n0 + wc * 64 + ni * 16 + col;
      C[base] = acc[mi][ni][0];
      C[base + N] = acc[mi][ni][1];
      C[base + 2 * (size_t)N] = acc[mi][ni][2];
      C[base + 3 * (size_t)N] = acc[mi][ni][3];
    }
#undef STG2
}

// ------- RoPE + cast to bf16: x[S][*] (stride ldx) -> y (stride ldy) bf16 ----
__global__ __launch_bounds__(256) void rope_cast(const float* __restrict__ x,
                                                 unsigned short* __restrict__ y,
                                                 int nheads, int ldx, int ldy) {
  int idx = blockIdx.x * 256 + threadIdx.x;
  int i = idx & 63;
  int rest = idx >> 6;
  int hh = rest % nheads;
  int s = rest / nheads;
  if (s >= S_LEN) return;
  const float* p = x + (size_t)s * ldx + hh * HD;
  unsigned short* o = y + (size_t)s * ldy + hh * HD;
  float inv = (float)(1.0 / pow(10000.0, (double)(2 * i) / 128.0));
  float ang = (float)s * inv;
  float c = cosf(ang);
  float sn = sinf(ang);
  float x1 = p[i];
  float x2 = p[i + 64];
  o[i] = f2bf(x1 * c - x2 * sn);
  o[i + 64] = f2bf(x2 * c + x1 * sn);
}

// ------------ fused heavy-hitter attention, MFMA, 16 q-rows, 8 waves ---------
template <int SMAX>
__global__ __launch_bounds__(512, 4)
void attn_mfma(const unsigned short* __restrict__ qb,
               const unsigned short* __restrict__ kb,
               const unsigned short* __restrict__ vt,
               unsigned short* __restrict__ ao16, int qbase) {
  const int qi0 = (qbase + blockIdx.x) << 4;
  const int h = blockIdx.y;
  const int g = h >> 2;
  const int tid = threadIdx.x;
  const int lane = tid & 63;
  const int wid = tid >> 6;          // 0..7
  const int col = lane & 15;
  const int quad = lane >> 4;
  const int nkm = qi0 + 16;
  const int nkm32 = (nkm + 31) & ~31;

  __shared__ __align__(16) unsigned short sc[16 * SMAX];
  __shared__ float sumv[16];

  // ---- Phase A: S = (Q K^T) * scale via MFMA, tiles stride-8, 2 deep ----
  short8 qf[4];
  {
    const unsigned short* qrow = qb + (size_t)(qi0 + col) * (NH * HD) + h * HD + (quad << 3);
#pragma unroll
    for (int dt = 0; dt < 4; ++dt) qf[dt] = *(const short8*)(qrow + dt * 32);
  }
  const int ntiles = nkm >> 4;
  int t = wid;
  for (; t + 8 < ntiles; t += 16) {
    const int k0a = t << 4;
    const int k0b = (t + 8) << 4;
    const unsigned short* kra = kb + (size_t)(k0a + col) * (NKV * HD) + g * HD + (quad << 3);
    const unsigned short* krb = kb + (size_t)(k0b + col) * (NKV * HD) + g * HD + (quad << 3);
    short8 kfa[4], kfb[4];
#pragma unroll
    for (int dt = 0; dt < 4; ++dt) kfa[dt] = *(const short8*)(kra + dt * 32);
#pragma unroll
    for (int dt = 0; dt < 4; ++dt) kfb[dt] = *(const short8*)(krb + dt * 32);
    float4v acca = {}, accb = {};
#pragma unroll
    for (int dt = 0; dt < 4; ++dt) {
      acca = __builtin_amdgcn_mfma_f32_16x16x32_bf16(qf[dt], kfa[dt], acca, 0, 0, 0);
      accb = __builtin_amdgcn_mfma_f32_16x16x32_bf16(qf[dt], kfb[dt], accb, 0, 0, 0);
    }
#pragma unroll
    for (int r = 0; r < 4; ++r) {
      int q = (quad << 2) + r;
      sc[(q * SMAX + k0a + col) ^ ((q & 7) << 3)] = f2bf(acca[r] * SCALE_QK);
      sc[(q * SMAX + k0b + col) ^ ((q & 7) << 3)] = f2bf(accb[r] * SCALE_QK);
    }
  }
  if (t < ntiles) {
    const int k0 = t << 4;
    const unsigned short* krow = kb + (size_t)(k0 + col) * (NKV * HD) + g * HD + (quad << 3);
    float4v acc = {};
#pragma unroll
    for (int dt = 0; dt < 4; ++dt) {
      short8 kf = *(const short8*)(krow + dt * 32);
      acc = __builtin_amdgcn_mfma_f32_16x16x32_bf16(qf[dt], kf, acc, 0, 0, 0);
    }
#pragma unroll
    for (int r = 0; r < 4; ++r) {
      int q = (quad << 2) + r;
      sc[(q * SMAX + k0 + col) ^ ((q & 7) << 3)] = f2bf(acc[r] * SCALE_QK);
    }
  }
  __syncthreads();

  // ---- Phase B: per-row top-k threshold + softmax (wave w owns rows 2w,2w+1) ----
  const unsigned long long lmlt = (1ull << lane) - 1ull;
#pragma unroll 1
  for (int rr = 0; rr < 2; ++rr) {
    const int r = (wid << 1) + rr;
    const int qi = qi0 + r;
    const int mhi = qi - RECENT_N;       // last middle index
    const int m = mhi - INIT_N + 1;      // middle count
    const bool need = (SMAX > 1024) && (m > HEAVY_N);
    const unsigned swz = (r & 7) << 3;
    const int rbase = r * SMAX;

    unsigned T = 0, rem = 0;
    if (need) {
      // 16-bit radix select over bf16 score keys; pads (0) never match target.
      unsigned myk[22];
#pragma unroll
      for (int j = 0; j < 11; ++j) {
        int off = (lane + (j << 6)) << 1;  // 0..1406 step 2, covers m <= 1408
        unsigned u = *(const unsigned*)&sc[(rbase + INIT_N + off) ^ swz];
        unsigned f0 = fkey16(u & 0xFFFFu);
        unsigned f1 = fkey16(u >> 16);
        myk[2 * j] = (off < m) ? f0 : 0u;
        myk[2 * j + 1] = (off + 1 < m) ? f1 : 0u;
      }
      unsigned prefix = 0, rm = HEAVY_N;
#pragma unroll 1
      for (int bit = 15; bit >= 0; --bit) {
        unsigned target = (prefix >> bit) | 1u;
        unsigned cnt = 0;
#pragma unroll
        for (int j = 0; j < 22; ++j)
          cnt += (unsigned)__popcll(__ballot((myk[j] >> bit) == target));
        if (cnt >= rm) prefix |= (1u << bit);
        else rm -= cnt;
      }
      T = prefix;
      rem = rm;
    }

    // Max over causal range only: the causal max is always in the selected set.
    float mx = -3.402823466e38f;
#pragma unroll 1
    for (int c0 = 0; c0 <= qi; c0 += 128) {
      int k2 = c0 + (lane << 1);
      unsigned u = *(const unsigned*)&sc[(rbase + k2) ^ swz];
      float s0 = bf2f(u & 0xFFFFu);
      float s1 = bf2f(u >> 16);
      if (k2 <= qi) mx = fmaxf(mx, s0);
      if (k2 + 1 <= qi) mx = fmaxf(mx, s1);
    }
#pragma unroll
    for (int off = 32; off; off >>= 1) mx = fmaxf(mx, __shfl_xor(mx, off, 64));

    float sum = 0.f;
    unsigned cum = 0;
#pragma unroll 1
    for (int c0 = 0; c0 < nkm32; c0 += 128) {
      int k2 = c0 + (lane << 1);
      int idx = (rbase + k2) ^ swz;
      unsigned u = *(const unsigned*)&sc[idx];
      bool ic0 = k2 <= qi, ic1 = (k2 + 1) <= qi;
      bool sel0, sel1;
      if (!need) {
        sel0 = ic0;
        sel1 = ic1;
      } else {
        bool mid0 = ic0 && (k2 >= INIT_N) && (k2 <= mhi);
        bool mid1 = ic1 && (k2 + 1 >= INIT_N) && (k2 + 1 <= mhi);
        unsigned f0 = fkey16(u & 0xFFFFu);
        unsigned f1 = fkey16(u >> 16);
        unsigned long long eq0 = __ballot(mid0 && (f0 == T));
        unsigned long long eq1 = __ballot(mid1 && (f1 == T));
        unsigned pre0 = cum + (unsigned)__popcll(eq0 & lmlt) + (unsigned)__popcll(eq1 & lmlt);
        unsigned pre1 = pre0 + (unsigned)((eq0 >> lane) & 1ull);
        sel0 = ic0 && (!mid0 || (f0 > T) || ((f0 == T) && (pre0 < rem)));
        sel1 = ic1 && (!mid1 || (f1 > T) || ((f1 == T) && (pre1 < rem)));
        cum += (unsigned)__popcll(eq0) + (unsigned)__popcll(eq1);
      }
      float e0 = sel0 ? __expf(bf2f(u & 0xFFFFu) - mx) : 0.f;
      float e1 = sel1 ? __expf(bf2f(u >> 16) - mx) : 0.f;
      sum += e0 + e1;
      *(unsigned*)&sc[idx] = (unsigned)f2bf(e0) | ((unsigned)f2bf(e1) << 16);
    }
#pragma unroll
    for (int off = 32; off; off >>= 1) sum += __shfl_xor(sum, off, 64);
    if (lane == 0) sumv[r] = sum;
  }
  __syncthreads();

  // ---- Phase C: O = P V via MFMA; wave w owns d-slice [16w, 16w+16) --------
  float4v a0 = {}, b0 = {};
  const int db = wid << 4;
  const unsigned short* vrow = vt + (size_t)(g * HD + db + col) * S_LEN + (quad << 3);
  const unsigned pswz = (unsigned)((col & 7) << 3);
  int k0 = 0;
  for (; k0 + 32 < nkm32; k0 += 64) {
    short8 pf0 = *(const short8*)&sc[(col * SMAX + k0 + (quad << 3)) ^ pswz];
    short8 pf1 = *(const short8*)&sc[(col * SMAX + k0 + 32 + (quad << 3)) ^ pswz];
    short8 v0 = *(const short8*)(vrow + k0);
    short8 v1 = *(const short8*)(vrow + k0 + 32);
    a0 = __builtin_amdgcn_mfma_f32_16x16x32_bf16(pf0, v0, a0, 0, 0, 0);
    b0 = __builtin_amdgcn_mfma_f32_16x16x32_bf16(pf1, v1, b0, 0, 0, 0);
  }
  if (k0 < nkm32) {
    short8 pf = *(const short8*)&sc[(col * SMAX + k0 + (quad << 3)) ^ pswz];
    short8 v0 = *(const short8*)(vrow + k0);
    a0 = __builtin_amdgcn_mfma_f32_16x16x32_bf16(pf, v0, a0, 0, 0, 0);
  }
  a0 += b0;
#pragma unroll
  for (int r = 0; r < 4; ++r) {
    int qq = (quad << 2) + r;
    float inv = 1.0f / sumv[qq];
    size_t o = (size_t)(qi0 + qq) * (NH * HD) + h * HD + db;
    ao16[o + col] = f2bf(a0[r] * inv);
  }
}

// ---------------------------------------------------------------------------
extern "C" void kernel_launch(void* const* d_in, const int* in_sizes, int n_in,
                              void* d_out, int out_size, void* d_ws, size_t ws_size,
                              hipStream_t stream) {
  const float* hidden = (const float*)d_in[0];
  const float* wq = (const float*)d_in[1];
  const float* wk = (const float*)d_in[2];
  const float* wv = (const float*)d_in[3];
  const float* wo = (const float*)d_in[4];
  float* out = (float*)d_out;

  // workspace layout (floats), 30M floats = 120 MB used:
  //  [ 0M,12M)  qkv f32 [S][6144] (q | k | v)  -> reused as P1 (split-K partial)
  //  [12M,16M)  qb16 bf16 [S][NH*HD]
  //  [16M,20M)  hb bf16 [S][HID]           -> reused as aob bf16
  //  [20M,32M)  wqkvT bf16 [6144][4096]    -> after QKV gemm reused:
  //               [20M,28M) woT bf16 [4096][4096]
  //               [28M,29M) kb16 bf16 [S][NKV*HD]
  //               [29M,30M) vT16 bf16 [NKV*HD][S]
  float* ws = (float*)d_ws;
  const size_t M1 = 1024 * 1024;
  float* qkv = ws;
  float* P1 = ws;                         // out-proj K-split partial (qkv dead by then)
  unsigned short* qb16 = (unsigned short*)(ws + 12 * M1);
  unsigned short* hb = (unsigned short*)(ws + 16 * M1);
  unsigned short* aob = hb;
  unsigned short* wqkvT = (unsigned short*)(ws + 20 * M1);
  unsigned short* woT = wqkvT;
  unsigned short* kb16 = (unsigned short*)(ws + 28 * M1);
  unsigned short* vT16 = (unsigned short*)(ws + 29 * M1);

  dim3 blk(256);
  const int NE = S_LEN * HID_N;  // 8,388,608

  cast_bf16x8<<<NE / 2048, blk, 0, stream>>>(hidden, hb, NE);
  transpose_cast<<<dim3(HID_N / 64, HID_N / 64), blk, 0, stream>>>(wq, wqkvT, HID_N, HID_N, HID_N);
  transpose_cast<<<dim3((NKV * HD) / 64, HID_N / 64), blk, 0, stream>>>(
      wk, wqkvT + (size_t)HID_N * HID_N, HID_N, NKV * HD, NKV * HD);
  transpose_cast<<<dim3((NKV * HD) / 64, HID_N / 64), blk, 0, stream>>>(
      wv, wqkvT + (size_t)(HID_N + NKV * HD) * HID_N, HID_N, NKV * HD, NKV * HD);

  // fused QKV projection: [2048][4096] @ [4096][6144] -> [2048][6144]
  gemm256<<<dim3(24, 8, 1), dim3(512), 0, stream>>>(hb, wqkvT, qkv, qkv, S_LEN, 6144,
                                                    HID_N, HID_N, HID_N);

  transpose_cast<<<dim3(HID_N / 64, HID_N / 64), blk, 0, stream>>>(wo, woT, NH * HD, HID_N, HID_N);

  rope_cast<<<(S_LEN * NH * 64) / 256, blk, 0, stream>>>(qkv, qb16, NH, 6144, NH * HD);
  rope_cast<<<(S_LEN * NKV * 64) / 256, blk, 0, stream>>>(qkv + HID_N, kb16, NKV, 6144, NKV * HD);
  transpose_cast<<<dim3((NKV * HD) / 64, S_LEN / 64), blk, 0, stream>>>(
      qkv + HID_N + NKV * HD, vT16, S_LEN, NKV * HD, 6144);

  attn_mfma<2048><<<dim3(64, NH), dim3(512), 0, stream>>>(qb16, kb16, vT16, aob, 64);
  attn_mfma<1024><<<dim3(64, NH), dim3(512), 0, stream>>>(qb16, kb16, vT16, aob, 0);

  // out-proj with split-K=2: 256 blocks (100% spatial), partials out/P1, then add
  gemm256<<<dim3(16, 8, 2), dim3(512), 0, stream>>>(aob, woT, out, P1, S_LEN, HID_N,
                                                    2048, NH * HD, HID_N);
  add_f32x4<<<NE / 1024, blk, 0, stream>>>(out, P1, NE);
}

// Round 8
// 805.149 us; speedup vs baseline: 1.1292x; 1.0087x over previous
//
#include <hip/hip_runtime.h>
#include <math.h>

#define S_LEN 2048
#define HID_N 4096
#define NH 32
#define NKV 8
#define HD 128
#define INIT_N 128
#define RECENT_N 512
#define HEAVY_N 512
#define SCALE_QK 0.08838834764831845f

typedef __attribute__((ext_vector_type(8))) short short8;
typedef __attribute__((ext_vector_type(4))) float float4v;

__device__ __forceinline__ unsigned short f2bf(float f) {
  unsigned u = __float_as_uint(f);
  unsigned r = (u + 0x7FFFu + ((u >> 16) & 1u)) >> 16;  // RNE (inputs finite)
  return (unsigned short)r;
}

__device__ __forceinline__ float bf2f(unsigned u) { return __uint_as_float(u << 16); }

__device__ __forceinline__ unsigned fkey16(unsigned u) {
  return (u & 0x8000u) ? ((~u) & 0xFFFFu) : (u | 0x8000u);
}

__device__ __forceinline__ void gld_lds16(const unsigned short* g, unsigned short* l) {
  __builtin_amdgcn_global_load_lds(
      (const __attribute__((address_space(1))) unsigned int*)g,
      (__attribute__((address_space(3))) unsigned int*)l, 16, 0, 0);
}

#define VMCNT(n) asm volatile("s_waitcnt vmcnt(" #n ")" ::: "memory")

// ---------------- elementwise cast fp32 -> bf16, 8 per thread ----------------
__global__ __launch_bounds__(256) void cast_bf16x8(const float* __restrict__ x,
                                                   unsigned short* __restrict__ y, int n) {
  int i = (blockIdx.x * 256 + threadIdx.x) << 3;
  if (i >= n) return;
  float4 a = *(const float4*)(x + i);
  float4 b = *(const float4*)(x + i + 4);
  union { unsigned short u[8]; short8 v; } o;
  o.u[0] = f2bf(a.x); o.u[1] = f2bf(a.y); o.u[2] = f2bf(a.z); o.u[3] = f2bf(a.w);
  o.u[4] = f2bf(b.x); o.u[5] = f2bf(b.y); o.u[6] = f2bf(b.z); o.u[7] = f2bf(b.w);
  *(short8*)(y + i) = o.v;
}

// ---------------- y += x, float4 per thread ---------------------------------
__global__ __launch_bounds__(256) void add_f32x4(float* __restrict__ y,
                                                 const float* __restrict__ x, int n) {
  int i = (blockIdx.x * 256 + threadIdx.x) << 2;
  if (i >= n) return;
  float4 a = *(const float4*)(y + i);
  float4 b = *(const float4*)(x + i);
  a.x += b.x; a.y += b.y; a.z += b.z; a.w += b.w;
  *(float4*)(y + i) = a;
}

// ------------- transpose + cast: w[R][C] (row stride ldw) -> wt[C][R] bf16 ---
__global__ __launch_bounds__(256) void transpose_cast(const float* __restrict__ w,
                                                      unsigned short* __restrict__ wt,
                                                      int R, int C, int ldw) {
  __shared__ unsigned short t[64][65];
  const int c0 = blockIdx.x * 64;
  const int r0 = blockIdx.y * 64;
  const int tx = threadIdx.x & 63;
  const int ty = threadIdx.x >> 6;
#pragma unroll
  for (int i = 0; i < 16; ++i)
    t[ty + 4 * i][tx] = f2bf(w[(size_t)(r0 + ty + 4 * i) * ldw + c0 + tx]);
  __syncthreads();
#pragma unroll
  for (int i = 0; i < 16; ++i)
    wt[(size_t)(c0 + ty + 4 * i) * R + r0 + tx] = t[tx][ty + 4 * i];
}

// ------ 256x256, BK=64, 8-phase pipelined bf16 GEMM: C = A[M][K] @ BT[N][K]^T
// 8 waves (2Mx4N), per-wave C = 128x64. T2 XOR-swizzled LDS (linear dest +
// pre-swizzled global source + swizzled ds_read, rule 21), counted vmcnt
// (never 0 mid-loop), setprio around MFMA clusters, XCD-aware block swizzle.
// blockIdx.z selects a K-slice of KT (split-K; partials to C0/C1).
__global__ __launch_bounds__(512, 2)
void gemm256(const unsigned short* __restrict__ A,
             const unsigned short* __restrict__ BT,
             float* __restrict__ C0, float* __restrict__ C1,
             int M, int N, int KT, int lda, int ldb) {
  __shared__ __align__(16) unsigned short lds[65536];  // A[2][256][64] | B[2][256][64]
  const int tid = threadIdx.x;
  const int lane = tid & 63;
  const int wid = tid >> 6;        // 0..7
  const int wr = wid >> 2;         // 0..1  (M)
  const int wc = wid & 3;          // 0..3  (N)
  const int col = lane & 15;
  const int quad = lane >> 4;

  A += (size_t)blockIdx.z * KT;
  BT += (size_t)blockIdx.z * KT;
  float* __restrict__ C = blockIdx.z ? C1 : C0;

  // XCD-aware swizzle of the per-slice linear block id (nwg % 8 == 0 here).
  const int gx = gridDim.x;
  const int nwg = gx * gridDim.y;
  int lin = blockIdx.y * gx + blockIdx.x;
  lin = (lin & 7) * (nwg >> 3) + (lin >> 3);
  const int m0 = (lin / gx) << 8;
  const int n0 = (lin % gx) << 8;
  const int NT = KT >> 6;

  const int sdst = wid << 9;       // wave-uniform LDS chunk (tid*8 = sdst + lane*8)
  const int grow = tid >> 3;       // 0..63 row within 64-row stage inst
  // T2: pre-swizzled global source column (dest row&7 == grow&7)
  const int gcolsw = ((tid & 7) << 3) ^ (((tid >> 3) & 7) << 3);
  // T2: read-side XOR (fragment rows have row&7 == col&7)
  const int o0 = ((quad << 3) ^ ((col & 7) << 3));   // k-group 0
  const int o1 = o0 ^ 32;                            // k-group +32

#define STG2(G, LD, GB, LOFF, RB0, RB1, KC)                                   \
  do {                                                                        \
    gld_lds16(G + (size_t)((GB) + (RB0) + grow) * (LD) + (KC) + gcolsw,       \
              &lds[(LOFF) + (RB0) * 64 + sdst]);                              \
    gld_lds16(G + (size_t)((GB) + (RB1) + grow) * (LD) + (KC) + gcolsw,       \
              &lds[(LOFF) + (RB1) * 64 + sdst]);                              \
  } while (0)

  float4v acc[8][4] = {};

  // ---- prologue ----
  STG2(BT, ldb, n0, 32768, 0, 64, 0);        // B0(0)
  STG2(BT, ldb, n0, 32768, 128, 192, 0);     // B1(0)
  STG2(A, lda, m0, 0, 0, 128, 0);            // A01(0)
  STG2(A, lda, m0, 0, 64, 192, 0);           // A23(0)
  if (NT > 1) {
    STG2(BT, ldb, n0, 32768 + 16384, 0, 64, 64);      // B0(1)
    STG2(BT, ldb, n0, 32768 + 16384, 128, 192, 64);   // B1(1)
    STG2(A, lda, m0, 16384, 0, 128, 64);              // A01(1)
    VMCNT(8);
  } else {
    VMCNT(2);
  }
  __builtin_amdgcn_s_barrier();

#pragma unroll 1
  for (int t = 0; t < NT; ++t) {
    const int cb = (t & 1) << 14;       // current A buf elem offset (0/16384)
    const int nb = cb ^ 16384;
    const int cbB = 32768 + cb;
    const int kc1 = (t + 1) << 6;
    const int kc2 = (t + 2) << 6;
    const bool h1 = (t + 1) < NT;
    const bool h2 = (t + 2) < NT;
    const int abase = cb + (wr * 128 + col) * 64;

    // ================= phase 0 =================
    short8 b8[4][2];
#pragma unroll
    for (int ni = 0; ni < 4; ++ni) {
      const int bb = cbB + (wc * 64 + ni * 16 + col) * 64;
      b8[ni][0] = *(const short8*)&lds[bb + o0];
      b8[ni][1] = *(const short8*)&lds[bb + o1];
    }
    {
      short8 x0 = *(const short8*)&lds[abase + 0 * 64 + o0];
      short8 x1 = *(const short8*)&lds[abase + 0 * 64 + o1];
      short8 x2 = *(const short8*)&lds[abase + 16 * 64 + o0];
      short8 x3 = *(const short8*)&lds[abase + 16 * 64 + o1];
      if (h1) STG2(A, lda, m0, nb, 64, 192, kc1);   // A23(t+1)
      __builtin_amdgcn_s_barrier();
      asm volatile("s_waitcnt lgkmcnt(0)" ::: "memory");
      __builtin_amdgcn_sched_barrier(0);
      __builtin_amdgcn_s_setprio(1);
#pragma unroll
      for (int ni = 0; ni < 4; ++ni) {
        acc[0][ni] = __builtin_amdgcn_mfma_f32_16x16x32_bf16(x0, b8[ni][0], acc[0][ni], 0, 0, 0);
        acc[0][ni] = __builtin_amdgcn_mfma_f32_16x16x32_bf16(x1, b8[ni][1], acc[0][ni], 0, 0, 0);
        acc[1][ni] = __builtin_amdgcn_mfma_f32_16x16x32_bf16(x2, b8[ni][0], acc[1][ni], 0, 0, 0);
        acc[1][ni] = __builtin_amdgcn_mfma_f32_16x16x32_bf16(x3, b8[ni][1], acc[1][ni], 0, 0, 0);
      }
      __builtin_amdgcn_s_setprio(0);
      __builtin_amdgcn_s_barrier();
    }
    // ================= phase 1 =================
    {
      short8 x0 = *(const short8*)&lds[abase + 32 * 64 + o0];
      short8 x1 = *(const short8*)&lds[abase + 32 * 64 + o1];
      short8 x2 = *(const short8*)&lds[abase + 48 * 64 + o0];
      short8 x3 = *(const short8*)&lds[abase + 48 * 64 + o1];
      if (h2) STG2(BT, ldb, n0, cbB, 0, 64, kc2);   // B0(t+2)
      if (h2) { VMCNT(10); } else if (h1) { VMCNT(8); } else { VMCNT(0); }  // certify A23(t)
      __builtin_amdgcn_s_barrier();
      asm volatile("s_waitcnt lgkmcnt(0)" ::: "memory");
      __builtin_amdgcn_sched_barrier(0);
      __builtin_amdgcn_s_setprio(1);
#pragma unroll
      for (int ni = 0; ni < 4; ++ni) {
        acc[2][ni] = __builtin_amdgcn_mfma_f32_16x16x32_bf16(x0, b8[ni][0], acc[2][ni], 0, 0, 0);
        acc[2][ni] = __builtin_amdgcn_mfma_f32_16x16x32_bf16(x1, b8[ni][1], acc[2][ni], 0, 0, 0);
        acc[3][ni] = __builtin_amdgcn_mfma_f32_16x16x32_bf16(x2, b8[ni][0], acc[3][ni], 0, 0, 0);
        acc[3][ni] = __builtin_amdgcn_mfma_f32_16x16x32_bf16(x3, b8[ni][1], acc[3][ni], 0, 0, 0);
      }
      __builtin_amdgcn_s_setprio(0);
      __builtin_amdgcn_s_barrier();
    }
    // ================= phase 2 =================
    {
      short8 x0 = *(const short8*)&lds[abase + 64 * 64 + o0];
      short8 x1 = *(const short8*)&lds[abase + 64 * 64 + o1];
      short8 x2 = *(const short8*)&lds[abase + 80 * 64 + o0];
      short8 x3 = *(const short8*)&lds[abase + 80 * 64 + o1];
      if (h2) STG2(BT, ldb, n0, cbB, 128, 192, kc2);  // B1(t+2)
      __builtin_amdgcn_s_barrier();
      asm volatile("s_waitcnt lgkmcnt(0)" ::: "memory");
      __builtin_amdgcn_sched_barrier(0);
      __builtin_amdgcn_s_setprio(1);
#pragma unroll
      for (int ni = 0; ni < 4; ++ni) {
        acc[4][ni] = __builtin_amdgcn_mfma_f32_16x16x32_bf16(x0, b8[ni][0], acc[4][ni], 0, 0, 0);
        acc[4][ni] = __builtin_amdgcn_mfma_f32_16x16x32_bf16(x1, b8[ni][1], acc[4][ni], 0, 0, 0);
        acc[5][ni] = __builtin_amdgcn_mfma_f32_16x16x32_bf16(x2, b8[ni][0], acc[5][ni], 0, 0, 0);
        acc[5][ni] = __builtin_amdgcn_mfma_f32_16x16x32_bf16(x3, b8[ni][1], acc[5][ni], 0, 0, 0);
      }
      __builtin_amdgcn_s_setprio(0);
      __builtin_amdgcn_s_barrier();
    }
    // ================= phase 3 =================
    {
      short8 x0 = *(const short8*)&lds[abase + 96 * 64 + o0];
      short8 x1 = *(const short8*)&lds[abase + 96 * 64 + o1];
      short8 x2 = *(const short8*)&lds[abase + 112 * 64 + o0];
      short8 x3 = *(const short8*)&lds[abase + 112 * 64 + o1];
      if (h2) STG2(A, lda, m0, cb, 0, 128, kc2);      // A01(t+2)
      if (h2) { VMCNT(8); } else if (h1) { VMCNT(2); }  // certify B(t+1)+A01(t+1)
      __builtin_amdgcn_s_barrier();
      asm volatile("s_waitcnt lgkmcnt(0)" ::: "memory");
      __builtin_amdgcn_sched_barrier(0);
      __builtin_amdgcn_s_setprio(1);
#pragma unroll
      for (int ni = 0; ni < 4; ++ni) {
        acc[6][ni] = __builtin_amdgcn_mfma_f32_16x16x32_bf16(x0, b8[ni][0], acc[6][ni], 0, 0, 0);
        acc[6][ni] = __builtin_amdgcn_mfma_f32_16x16x32_bf16(x1, b8[ni][1], acc[6][ni], 0, 0, 0);
        acc[7][ni] = __builtin_amdgcn_mfma_f32_16x16x32_bf16(x2, b8[ni][0], acc[7][ni], 0, 0, 0);
        acc[7][ni] = __builtin_amdgcn_mfma_f32_16x16x32_bf16(x3, b8[ni][1], acc[7][ni], 0, 0, 0);
      }
      __builtin_amdgcn_s_setprio(0);
      __builtin_amdgcn_s_barrier();
    }
  }

#pragma unroll
  for (int mi = 0; mi < 8; ++mi)
#pragma unroll
    for (int ni = 0; ni < 4; ++ni) {
      size_t base = (size_t)(m0 + wr * 128 + mi * 16 + (quad << 2)) * N +
                    n0 + wc * 64 + ni * 16 + col;
      C[base] = acc[mi][ni][0];
      C[base + N] = acc[mi][ni][1];
      C[base + 2 * (size_t)N] = acc[mi][ni][2];
      C[base + 3 * (size_t)N] = acc[mi][ni][3];
    }
#undef STG2
}

// ------- RoPE + cast to bf16: x[S][*] (stride ldx) -> y (stride ldy) bf16 ----
__global__ __launch_bounds__(256) void rope_cast(const float* __restrict__ x,
                                                 unsigned short* __restrict__ y,
                                                 int nheads, int ldx, int ldy) {
  int idx = blockIdx.x * 256 + threadIdx.x;
  int i = idx & 63;
  int rest = idx >> 6;
  int hh = rest % nheads;
  int s = rest / nheads;
  if (s >= S_LEN) return;
  const float* p = x + (size_t)s * ldx + hh * HD;
  unsigned short* o = y + (size_t)s * ldy + hh * HD;
  float inv = (float)(1.0 / pow(10000.0, (double)(2 * i) / 128.0));
  float ang = (float)s * inv;
  float c = cosf(ang);
  float sn = sinf(ang);
  float x1 = p[i];
  float x2 = p[i + 64];
  o[i] = f2bf(x1 * c - x2 * sn);
  o[i + 64] = f2bf(x2 * c + x1 * sn);
}

// ------------ fused heavy-hitter attention, MFMA, 16 q-rows, 8 waves ---------
// Phase B fused-2-row ILP: wave w owns rows w and w+8, interleaved (the radix
// and softmax serial chains were dependency-stall-bound at 41% VALU duty;
// two independent chains per wave dual-issue).
template <int SMAX>
__global__ __launch_bounds__(512, 4)
void attn_mfma(const unsigned short* __restrict__ qb,
               const unsigned short* __restrict__ kb,
               const unsigned short* __restrict__ vt,
               unsigned short* __restrict__ ao16, int qbase) {
  const int qi0 = (qbase + blockIdx.x) << 4;
  const int h = blockIdx.y;
  const int g = h >> 2;
  const int tid = threadIdx.x;
  const int lane = tid & 63;
  const int wid = tid >> 6;          // 0..7
  const int col = lane & 15;
  const int quad = lane >> 4;
  const int nkm = qi0 + 16;
  const int nkm32 = (nkm + 31) & ~31;

  __shared__ __align__(16) unsigned short sc[16 * SMAX];
  __shared__ float sumv[16];

  // ---- Phase A: S = (Q K^T) * scale via MFMA, tiles stride-8, 2 deep ----
  short8 qf[4];
  {
    const unsigned short* qrow = qb + (size_t)(qi0 + col) * (NH * HD) + h * HD + (quad << 3);
#pragma unroll
    for (int dt = 0; dt < 4; ++dt) qf[dt] = *(const short8*)(qrow + dt * 32);
  }
  const int ntiles = nkm >> 4;
  int t = wid;
  for (; t + 8 < ntiles; t += 16) {
    const int k0a = t << 4;
    const int k0b = (t + 8) << 4;
    const unsigned short* kra = kb + (size_t)(k0a + col) * (NKV * HD) + g * HD + (quad << 3);
    const unsigned short* krb = kb + (size_t)(k0b + col) * (NKV * HD) + g * HD + (quad << 3);
    short8 kfa[4], kfb[4];
#pragma unroll
    for (int dt = 0; dt < 4; ++dt) kfa[dt] = *(const short8*)(kra + dt * 32);
#pragma unroll
    for (int dt = 0; dt < 4; ++dt) kfb[dt] = *(const short8*)(krb + dt * 32);
    float4v acca = {}, accb = {};
#pragma unroll
    for (int dt = 0; dt < 4; ++dt) {
      acca = __builtin_amdgcn_mfma_f32_16x16x32_bf16(qf[dt], kfa[dt], acca, 0, 0, 0);
      accb = __builtin_amdgcn_mfma_f32_16x16x32_bf16(qf[dt], kfb[dt], accb, 0, 0, 0);
    }
#pragma unroll
    for (int r = 0; r < 4; ++r) {
      int q = (quad << 2) + r;
      sc[(q * SMAX + k0a + col) ^ ((q & 7) << 3)] = f2bf(acca[r] * SCALE_QK);
      sc[(q * SMAX + k0b + col) ^ ((q & 7) << 3)] = f2bf(accb[r] * SCALE_QK);
    }
  }
  if (t < ntiles) {
    const int k0 = t << 4;
    const unsigned short* krow = kb + (size_t)(k0 + col) * (NKV * HD) + g * HD + (quad << 3);
    float4v acc = {};
#pragma unroll
    for (int dt = 0; dt < 4; ++dt) {
      short8 kf = *(const short8*)(krow + dt * 32);
      acc = __builtin_amdgcn_mfma_f32_16x16x32_bf16(qf[dt], kf, acc, 0, 0, 0);
    }
#pragma unroll
    for (int r = 0; r < 4; ++r) {
      int q = (quad << 2) + r;
      sc[(q * SMAX + k0 + col) ^ ((q & 7) << 3)] = f2bf(acc[r] * SCALE_QK);
    }
  }
  __syncthreads();

  // ---- Phase B (fused): wave w owns rows rA=w and rB=w+8, interleaved ----
  const unsigned long long lmlt = (1ull << lane) - 1ull;
  {
    const int rA = wid, rB = wid + 8;
    const int qiA = qi0 + rA, qiB = qi0 + rB;
    const int mhiA = qiA - RECENT_N, mhiB = qiB - RECENT_N;
    const int mA = mhiA - INIT_N + 1, mB = mhiB - INIT_N + 1;
    const bool needA = (SMAX > 1024) && (mA > HEAVY_N);
    const bool needB = (SMAX > 1024) && (mB > HEAVY_N);
    const unsigned swzA = (rA & 7) << 3, swzB = (rB & 7) << 3;
    const int rbA = rA * SMAX, rbB = rB * SMAX;

    unsigned TA = 0, remA = 0, TB = 0, remB = 0;
    if (needA | needB) {
      // 16-bit radix select, both rows interleaved. Pads (0) never match
      // target (target low bit always 1); a !need row's keys are all 0.
      unsigned mykA[22], mykB[22];
#pragma unroll
      for (int j = 0; j < 11; ++j) {
        int off = (lane + (j << 6)) << 1;  // 0..1407, covers m <= 1408
        unsigned uA = *(const unsigned*)&sc[(rbA + INIT_N + off) ^ swzA];
        unsigned uB = *(const unsigned*)&sc[(rbB + INIT_N + off) ^ swzB];
        mykA[2 * j] = (needA && off < mA) ? fkey16(uA & 0xFFFFu) : 0u;
        mykA[2 * j + 1] = (needA && off + 1 < mA) ? fkey16(uA >> 16) : 0u;
        mykB[2 * j] = (needB && off < mB) ? fkey16(uB & 0xFFFFu) : 0u;
        mykB[2 * j + 1] = (needB && off + 1 < mB) ? fkey16(uB >> 16) : 0u;
      }
      unsigned pA = 0, rmA = HEAVY_N, pB = 0, rmB = HEAVY_N;
#pragma unroll 1
      for (int bit = 15; bit >= 0; --bit) {
        unsigned tgA = (pA >> bit) | 1u;
        unsigned tgB = (pB >> bit) | 1u;
        unsigned cA = 0, cB = 0;
#pragma unroll
        for (int j = 0; j < 22; ++j) {
          cA += (unsigned)__popcll(__ballot((mykA[j] >> bit) == tgA));
          cB += (unsigned)__popcll(__ballot((mykB[j] >> bit) == tgB));
        }
        if (cA >= rmA) pA |= (1u << bit); else rmA -= cA;
        if (cB >= rmB) pB |= (1u << bit); else rmB -= cB;
      }
      TA = pA; remA = rmA; TB = pB; remB = rmB;
    }

    // Fused max pass over causal ranges (causal max is always selected).
    float mxA = -3.402823466e38f, mxB = -3.402823466e38f;
#pragma unroll 1
    for (int c0 = 0; c0 <= qiB; c0 += 128) {
      int k2 = c0 + (lane << 1);
      unsigned uA = *(const unsigned*)&sc[(rbA + k2) ^ swzA];
      unsigned uB = *(const unsigned*)&sc[(rbB + k2) ^ swzB];
      if (k2 <= qiA) mxA = fmaxf(mxA, bf2f(uA & 0xFFFFu));
      if (k2 + 1 <= qiA) mxA = fmaxf(mxA, bf2f(uA >> 16));
      if (k2 <= qiB) mxB = fmaxf(mxB, bf2f(uB & 0xFFFFu));
      if (k2 + 1 <= qiB) mxB = fmaxf(mxB, bf2f(uB >> 16));
    }
#pragma unroll
    for (int off = 32; off; off >>= 1) {
      mxA = fmaxf(mxA, __shfl_xor(mxA, off, 64));
      mxB = fmaxf(mxB, __shfl_xor(mxB, off, 64));
    }

    // Fused select + exp + sum pass.
    float sumA = 0.f, sumB = 0.f;
    unsigned cumA = 0, cumB = 0;
#pragma unroll 1
    for (int c0 = 0; c0 < nkm32; c0 += 128) {
      int k2 = c0 + (lane << 1);
      int idxA = (rbA + k2) ^ swzA;
      int idxB = (rbB + k2) ^ swzB;
      unsigned uA = *(const unsigned*)&sc[idxA];
      unsigned uB = *(const unsigned*)&sc[idxB];
      bool icA0 = k2 <= qiA, icA1 = (k2 + 1) <= qiA;
      bool icB0 = k2 <= qiB, icB1 = (k2 + 1) <= qiB;
      bool selA0, selA1, selB0, selB1;
      if (!needA) { selA0 = icA0; selA1 = icA1; }
      else {
        bool mid0 = icA0 && (k2 >= INIT_N) && (k2 <= mhiA);
        bool mid1 = icA1 && (k2 + 1 >= INIT_N) && (k2 + 1 <= mhiA);
        unsigned f0 = fkey16(uA & 0xFFFFu);
        unsigned f1 = fkey16(uA >> 16);
        unsigned long long eq0 = __ballot(mid0 && (f0 == TA));
        unsigned long long eq1 = __ballot(mid1 && (f1 == TA));
        unsigned pre0 = cumA + (unsigned)__popcll(eq0 & lmlt) + (unsigned)__popcll(eq1 & lmlt);
        unsigned pre1 = pre0 + (unsigned)((eq0 >> lane) & 1ull);
        selA0 = icA0 && (!mid0 || (f0 > TA) || ((f0 == TA) && (pre0 < remA)));
        selA1 = icA1 && (!mid1 || (f1 > TA) || ((f1 == TA) && (pre1 < remA)));
        cumA += (unsigned)__popcll(eq0) + (unsigned)__popcll(eq1);
      }
      if (!needB) { selB0 = icB0; selB1 = icB1; }
      else {
        bool mid0 = icB0 && (k2 >= INIT_N) && (k2 <= mhiB);
        bool mid1 = icB1 && (k2 + 1 >= INIT_N) && (k2 + 1 <= mhiB);
        unsigned f0 = fkey16(uB & 0xFFFFu);
        unsigned f1 = fkey16(uB >> 16);
        unsigned long long eq0 = __ballot(mid0 && (f0 == TB));
        unsigned long long eq1 = __ballot(mid1 && (f1 == TB));
        unsigned pre0 = cumB + (unsigned)__popcll(eq0 & lmlt) + (unsigned)__popcll(eq1 & lmlt);
        unsigned pre1 = pre0 + (unsigned)((eq0 >> lane) & 1ull);
        selB0 = icB0 && (!mid0 || (f0 > TB) || ((f0 == TB) && (pre0 < remB)));
        selB1 = icB1 && (!mid1 || (f1 > TB) || ((f1 == TB) && (pre1 < remB)));
        cumB += (unsigned)__popcll(eq0) + (unsigned)__popcll(eq1);
      }
      float eA0 = selA0 ? __expf(bf2f(uA & 0xFFFFu) - mxA) : 0.f;
      float eA1 = selA1 ? __expf(bf2f(uA >> 16) - mxA) : 0.f;
      float eB0 = selB0 ? __expf(bf2f(uB & 0xFFFFu) - mxB) : 0.f;
      float eB1 = selB1 ? __expf(bf2f(uB >> 16) - mxB) : 0.f;
      sumA += eA0 + eA1;
      sumB += eB0 + eB1;
      *(unsigned*)&sc[idxA] = (unsigned)f2bf(eA0) | ((unsigned)f2bf(eA1) << 16);
      *(unsigned*)&sc[idxB] = (unsigned)f2bf(eB0) | ((unsigned)f2bf(eB1) << 16);
    }
#pragma unroll
    for (int off = 32; off; off >>= 1) {
      sumA += __shfl_xor(sumA, off, 64);
      sumB += __shfl_xor(sumB, off, 64);
    }
    if (lane == 0) { sumv[rA] = sumA; sumv[rB] = sumB; }
  }
  __syncthreads();

  // ---- Phase C: O = P V via MFMA; wave w owns d-slice [16w, 16w+16) --------
  float4v a0 = {}, b0 = {};
  const int db = wid << 4;
  const unsigned short* vrow = vt + (size_t)(g * HD + db + col) * S_LEN + (quad << 3);
  const unsigned pswz = (unsigned)((col & 7) << 3);
  int k0 = 0;
  for (; k0 + 32 < nkm32; k0 += 64) {
    short8 pf0 = *(const short8*)&sc[(col * SMAX + k0 + (quad << 3)) ^ pswz];
    short8 pf1 = *(const short8*)&sc[(col * SMAX + k0 + 32 + (quad << 3)) ^ pswz];
    short8 v0 = *(const short8*)(vrow + k0);
    short8 v1 = *(const short8*)(vrow + k0 + 32);
    a0 = __builtin_amdgcn_mfma_f32_16x16x32_bf16(pf0, v0, a0, 0, 0, 0);
    b0 = __builtin_amdgcn_mfma_f32_16x16x32_bf16(pf1, v1, b0, 0, 0, 0);
  }
  if (k0 < nkm32) {
    short8 pf = *(const short8*)&sc[(col * SMAX + k0 + (quad << 3)) ^ pswz];
    short8 v0 = *(const short8*)(vrow + k0);
    a0 = __builtin_amdgcn_mfma_f32_16x16x32_bf16(pf, v0, a0, 0, 0, 0);
  }
  a0 += b0;
#pragma unroll
  for (int r = 0; r < 4; ++r) {
    int qq = (quad << 2) + r;
    float inv = 1.0f / sumv[qq];
    size_t o = (size_t)(qi0 + qq) * (NH * HD) + h * HD + db;
    ao16[o + col] = f2bf(a0[r] * inv);
  }
}

// ---------------------------------------------------------------------------
extern "C" void kernel_launch(void* const* d_in, const int* in_sizes, int n_in,
                              void* d_out, int out_size, void* d_ws, size_t ws_size,
                              hipStream_t stream) {
  const float* hidden = (const float*)d_in[0];
  const float* wq = (const float*)d_in[1];
  const float* wk = (const float*)d_in[2];
  const float* wv = (const float*)d_in[3];
  const float* wo = (const float*)d_in[4];
  float* out = (float*)d_out;

  // workspace layout (floats), 30M floats = 120 MB used:
  //  [ 0M,12M)  qkv f32 [S][6144] (q | k | v)  -> reused as P1 (split-K partial)
  //  [12M,16M)  qb16 bf16 [S][NH*HD]
  //  [16M,20M)  hb bf16 [S][HID]           -> reused as aob bf16
  //  [20M,32M)  wqkvT bf16 [6144][4096]    -> after QKV gemm reused:
  //               [20M,28M) woT bf16 [4096][4096]
  //               [28M,29M) kb16 bf16 [S][NKV*HD]
  //               [29M,30M) vT16 bf16 [NKV*HD][S]
  float* ws = (float*)d_ws;
  const size_t M1 = 1024 * 1024;
  float* qkv = ws;
  float* P1 = ws;                         // out-proj K-split partial (qkv dead by then)
  unsigned short* qb16 = (unsigned short*)(ws + 12 * M1);
  unsigned short* hb = (unsigned short*)(ws + 16 * M1);
  unsigned short* aob = hb;
  unsigned short* wqkvT = (unsigned short*)(ws + 20 * M1);
  unsigned short* woT = wqkvT;
  unsigned short* kb16 = (unsigned short*)(ws + 28 * M1);
  unsigned short* vT16 = (unsigned short*)(ws + 29 * M1);

  dim3 blk(256);
  const int NE = S_LEN * HID_N;  // 8,388,608

  cast_bf16x8<<<NE / 2048, blk, 0, stream>>>(hidden, hb, NE);
  transpose_cast<<<dim3(HID_N / 64, HID_N / 64), blk, 0, stream>>>(wq, wqkvT, HID_N, HID_N, HID_N);
  transpose_cast<<<dim3((NKV * HD) / 64, HID_N / 64), blk, 0, stream>>>(
      wk, wqkvT + (size_t)HID_N * HID_N, HID_N, NKV * HD, NKV * HD);
  transpose_cast<<<dim3((NKV * HD) / 64, HID_N / 64), blk, 0, stream>>>(
      wv, wqkvT + (size_t)(HID_N + NKV * HD) * HID_N, HID_N, NKV * HD, NKV * HD);

  // fused QKV projection: [2048][4096] @ [4096][6144] -> [2048][6144]
  gemm256<<<dim3(24, 8, 1), dim3(512), 0, stream>>>(hb, wqkvT, qkv, qkv, S_LEN, 6144,
                                                    HID_N, HID_N, HID_N);

  transpose_cast<<<dim3(HID_N / 64, HID_N / 64), blk, 0, stream>>>(wo, woT, NH * HD, HID_N, HID_N);

  rope_cast<<<(S_LEN * NH * 64) / 256, blk, 0, stream>>>(qkv, qb16, NH, 6144, NH * HD);
  rope_cast<<<(S_LEN * NKV * 64) / 256, blk, 0, stream>>>(qkv + HID_N, kb16, NKV, 6144, NKV * HD);
  transpose_cast<<<dim3((NKV * HD) / 64, S_LEN / 64), blk, 0, stream>>>(
      qkv + HID_N + NKV * HD, vT16, S_LEN, NKV * HD, 6144);

  attn_mfma<2048><<<dim3(64, NH), dim3(512), 0, stream>>>(qb16, kb16, vT16, aob, 64);
  attn_mfma<1024><<<dim3(64, NH), dim3(512), 0, stream>>>(qb16, kb16, vT16, aob, 0);

  // out-proj with split-K=2: 256 blocks (100% spatial), partials out/P1, then add
  gemm256<<<dim3(16, 8, 2), dim3(512), 0, stream>>>(aob, woT, out, P1, S_LEN, HID_N,
                                                    2048, NH * HD, HID_N);
  add_f32x4<<<NE / 1024, blk, 0, stream>>>(out, P1, NE);
}